// Round 5
// baseline (168.086 us; speedup 1.0000x reference)
//
#include <hip/hip_runtime.h>

// Problem dims (hard-coded in reference)
#define DD   768
#define NN   512
#define MM   512

#define PRE_K 2.88539008177792681472f   // 2*log2(e)

__device__ __forceinline__ float fexp(float x) { return __builtin_amdgcn_exp2f(x); }
__device__ __forceinline__ float frcp(float x) { return __builtin_amdgcn_rcpf(x); }
// tanh(x) = 1 - 2/(1 + e^{2x}); saturates correctly via exp2->inf/0 + rcp.
__device__ __forceinline__ float fast_tanh(float x) {
  return 1.0f - 2.0f * frcp(fexp(PRE_K * x) + 1.0f);
}

// ---- 32x64 fp32 GEMM tile, double-buffered LDS, K-range, scaled store ------
// Out[i,j] = scale * sum_{k in range} X[i,k] * (TRANSB ? W[j,k] : W[k,j])
#define XLD 34   // 32+2: keeps 8B align for b64 reads
#define WLD 68   // 64+4: keeps 16B align for b128 reads

template <bool TRANSB>
__device__ __forceinline__ void gemm_tile32(
    const float* __restrict__ X, const float* __restrict__ W,
    float* __restrict__ Out, int ldo,
    int i0, int j0, int ldx, int ldw, int k0, int ksteps, float scale)
{
  __shared__ float Xs[2][16][XLD];   // [buf][k][row]
  __shared__ float Ws[2][16][WLD];   // [buf][k][col]
  const int tid  = threadIdx.x;
  // X staging: 32 rows x 16 k = 512 floats, one float2 per thread
  const int xrow = tid >> 3;            // 0..31
  const int xk   = (tid & 7) << 1;      // 0,2,..,14
  const float* xp = &X[(size_t)(i0 + xrow) * ldx + k0 + xk];
  // W staging: 16 k x 64 cols = 1024 floats, one float4 per thread
  const float* wp = TRANSB
      ? &W[(size_t)(j0 + (tid >> 2)) * ldw + k0 + ((tid & 3) << 2)]
      : &W[(size_t)(k0 + (tid >> 4)) * ldw + j0 + ((tid & 15) << 2)];

  const int ng = tid >> 4;     // 0..15 -> rows 2ng, 2ng+1
  const int mg = tid & 15;     // 0..15 -> cols 4mg..4mg+3

  // prefetch step 0
  float2 xv = *(const float2*)xp;
  float4 wv = *(const float4*)wp;

  float acc[2][4] = {};
  int p = 0;

  Xs[0][xk][xrow] = xv.x; Xs[0][xk + 1][xrow] = xv.y;
  if (TRANSB) {
    const int c = tid >> 2, kq = (tid & 3) << 2;
    Ws[0][kq + 0][c] = wv.x; Ws[0][kq + 1][c] = wv.y;
    Ws[0][kq + 2][c] = wv.z; Ws[0][kq + 3][c] = wv.w;
  } else {
    *(float4*)&Ws[0][tid >> 4][(tid & 15) << 2] = wv;
  }
  __syncthreads();

  for (int s = 0; s < ksteps; ++s) {
    const bool more = (s + 1 < ksteps);
    if (more) {
      xv = *(const float2*)(xp + (s + 1) * 16);
      wv = TRANSB ? *(const float4*)(wp + (s + 1) * 16)
                  : *(const float4*)(wp + (size_t)(s + 1) * 16 * ldw);
    }
    #pragma unroll
    for (int kk = 0; kk < 16; ++kk) {
      const float2 xr = *(const float2*)&Xs[p][kk][ng << 1];
      const float4 wr = *(const float4*)&Ws[p][kk][mg << 2];
      acc[0][0] = fmaf(xr.x, wr.x, acc[0][0]);
      acc[0][1] = fmaf(xr.x, wr.y, acc[0][1]);
      acc[0][2] = fmaf(xr.x, wr.z, acc[0][2]);
      acc[0][3] = fmaf(xr.x, wr.w, acc[0][3]);
      acc[1][0] = fmaf(xr.y, wr.x, acc[1][0]);
      acc[1][1] = fmaf(xr.y, wr.y, acc[1][1]);
      acc[1][2] = fmaf(xr.y, wr.z, acc[1][2]);
      acc[1][3] = fmaf(xr.y, wr.w, acc[1][3]);
    }
    if (more) {
      const int q = p ^ 1;
      Xs[q][xk][xrow] = xv.x; Xs[q][xk + 1][xrow] = xv.y;
      if (TRANSB) {
        const int c = tid >> 2, kq = (tid & 3) << 2;
        Ws[q][kq + 0][c] = wv.x; Ws[q][kq + 1][c] = wv.y;
        Ws[q][kq + 2][c] = wv.z; Ws[q][kq + 3][c] = wv.w;
      } else {
        *(float4*)&Ws[q][tid >> 4][(tid & 15) << 2] = wv;
      }
    }
    __syncthreads();
    p ^= 1;
  }

  #pragma unroll
  for (int r = 0; r < 2; ++r) {
    float4 o;
    o.x = acc[r][0] * scale; o.y = acc[r][1] * scale;
    o.z = acc[r][2] * scale; o.w = acc[r][3] * scale;
    *(float4*)&Out[(size_t)(i0 + (ng << 1) + r) * ldo + j0 + (mg << 2)] = o;
  }
}

// z 0: A = text@W1 ; 1: kw2t = PRE_K*(text@W2) ; 2: kw3v = PRE_K*(visual@W3^T)
// Full K=768, direct final outputs (no partials / reduce pass). 576 blocks.
__global__ __launch_bounds__(256) void gemm3_kernel(
    const float* __restrict__ text, const float* __restrict__ visual,
    const float* __restrict__ W1, const float* __restrict__ W2,
    const float* __restrict__ W3,
    float* __restrict__ A, float* __restrict__ kw2t, float* __restrict__ kw3v)
{
  const int i0 = blockIdx.y * 32;
  const int j0 = blockIdx.x * 64;
  const int z  = blockIdx.z;
  if (z == 0)
    gemm_tile32<false>(text,   W1, A,    DD, i0, j0, DD, DD, 0, 48, 1.0f);
  else if (z == 1)
    gemm_tile32<false>(text,   W2, kw2t, DD, i0, j0, DD, DD, 0, 48, PRE_K);
  else
    gemm_tile32<true >(visual, W3, kw3v, DD, i0, j0, DD, DD, 0, 48, PRE_K);
}

// Q[z] = A @ visual^T over K range z*192..+192  (4-way split, 512 blocks)
__global__ __launch_bounds__(256) void cgemm_kernel(
    const float* __restrict__ A, const float* __restrict__ visual,
    float* __restrict__ Q)
{
  const int i0 = blockIdx.y * 32;
  const int j0 = blockIdx.x * 64;
  const int z  = blockIdx.z;
  gemm_tile32<true>(A, visual, Q + (size_t)z * NN * MM, MM,
                    i0, j0, DD, DD, z * (DD / 4), 12, 1.0f);
}

// T[n] = sum_d text[n,d]
__global__ __launch_bounds__(64) void tsum_kernel(
    const float* __restrict__ text, float* __restrict__ T)
{
  const int n = blockIdx.x;
  const int lane = threadIdx.x;
  float s = 0.f;
  #pragma unroll
  for (int i = 0; i < DD / 64; ++i) s += text[n * DD + lane + i * 64];
  #pragma unroll
  for (int off = 32; off; off >>= 1) s += __shfl_down(s, off);
  if (lane == 0) T[n] = s;
}

// ---- main fused kernel (d-split x2 for occupancy) --------------------------
// cval = tanh(sum_z Q[z][n,m])
// Spart[z][n,m] = sum_{d in half z} text[n,d]*rcp(1 + exp2(kw2t[n,d] + kw3v[m,d]*cval))
// Tile 16n x 32m, 2 m per thread (R4's busy-cycle win) + z-split to keep
// 1024 blocks = 4 waves/SIMD (R4 lesson: 512 blocks = 2 w/SIMD stalled).
#define DCH    64        // d-chunk staged per iteration
#define DRANGE 384       // d per z-slice
#define MLDW   68        // LDS row stride (64+4, 16B-aligned)

__global__ __launch_bounds__(256) void main_kernel(
    const float* __restrict__ text, const float* __restrict__ kw2t,
    const float* __restrict__ kw3v, const float* __restrict__ Q,
    float* __restrict__ Spart)
{
  __shared__ float ts[16][MLDW];
  __shared__ float w2s[16][MLDW];
  __shared__ float w3s[32][MLDW];

  const int tid = threadIdx.x;
  const int nl = tid >> 4;            // 0..15
  const int ml = tid & 15;            // 0..15
  const int n0 = blockIdx.y * 16;
  const int m0 = blockIdx.x * 32;
  const int z  = blockIdx.z;
  const int n  = n0 + nl;
  const int mA = m0 + ml, mB = mA + 16;
  const int dbase = z * DRANGE;

  // cval = tanh(sum of 4 Craw partials), per owned m
  float cA = 0.f, cB = 0.f;
  #pragma unroll
  for (int zz = 0; zz < 4; ++zz) {
    const float* q = Q + (size_t)zz * NN * MM + (size_t)n * MM;
    cA += q[mA]; cB += q[mB];
  }
  cA = fast_tanh(cA); cB = fast_tanh(cB);

  float4 aA = {0.f, 0.f, 0.f, 0.f};
  float4 aB = {0.f, 0.f, 0.f, 0.f};

  const int srow = tid >> 4;              // staging row 0..15
  const int sc4  = (tid & 15) << 2;       // staging col 0..60

  for (int dc = 0; dc < DRANGE; dc += DCH) {
    const int d0 = dbase + dc;
    *(float4*)&ts[srow][sc4]       = *(const float4*)&text[(size_t)(n0 + srow) * DD + d0 + sc4];
    *(float4*)&w2s[srow][sc4]      = *(const float4*)&kw2t[(size_t)(n0 + srow) * DD + d0 + sc4];
    *(float4*)&w3s[srow][sc4]      = *(const float4*)&kw3v[(size_t)(m0 + srow) * DD + d0 + sc4];
    *(float4*)&w3s[srow + 16][sc4] = *(const float4*)&kw3v[(size_t)(m0 + 16 + srow) * DD + d0 + sc4];
    __syncthreads();

    #pragma unroll 4
    for (int j = 0; j < DCH; j += 4) {
      const float4 tv  = *(const float4*)&ts[nl][j];
      const float4 w2  = *(const float4*)&w2s[nl][j];
      const float4 w3A = *(const float4*)&w3s[ml][j];
      const float4 w3B = *(const float4*)&w3s[ml + 16][j];
      aA.x = fmaf(tv.x, frcp(fexp(fmaf(w3A.x, cA, w2.x)) + 1.0f), aA.x);
      aA.y = fmaf(tv.y, frcp(fexp(fmaf(w3A.y, cA, w2.y)) + 1.0f), aA.y);
      aA.z = fmaf(tv.z, frcp(fexp(fmaf(w3A.z, cA, w2.z)) + 1.0f), aA.z);
      aA.w = fmaf(tv.w, frcp(fexp(fmaf(w3A.w, cA, w2.w)) + 1.0f), aA.w);
      aB.x = fmaf(tv.x, frcp(fexp(fmaf(w3B.x, cB, w2.x)) + 1.0f), aB.x);
      aB.y = fmaf(tv.y, frcp(fexp(fmaf(w3B.y, cB, w2.y)) + 1.0f), aB.y);
      aB.z = fmaf(tv.z, frcp(fexp(fmaf(w3B.z, cB, w2.z)) + 1.0f), aB.z);
      aB.w = fmaf(tv.w, frcp(fexp(fmaf(w3B.w, cB, w2.w)) + 1.0f), aB.w);
    }
    __syncthreads();
  }

  float* Sp = Spart + (size_t)z * NN * MM + (size_t)n * MM;
  Sp[mA] = (aA.x + aA.y) + (aA.z + aA.w);
  Sp[mB] = (aB.x + aB.y) + (aB.z + aB.w);
}

// out[n,m] = T[n] - 2*(Spart0 + Spart1)
__global__ __launch_bounds__(256) void combine_kernel(
    const float* __restrict__ Spart, const float* __restrict__ T,
    float* __restrict__ out)
{
  const size_t i = ((size_t)blockIdx.x * 256 + threadIdx.x) * 4;
  const int n = (int)(i >> 9);   // /512 (MM)
  const float Tn = T[n];
  const float4 s0 = *(const float4*)&Spart[i];
  const float4 s1 = *(const float4*)&Spart[(size_t)NN * MM + i];
  float4 o;
  o.x = Tn - 2.0f * (s0.x + s1.x);
  o.y = Tn - 2.0f * (s0.y + s1.y);
  o.z = Tn - 2.0f * (s0.z + s1.z);
  o.w = Tn - 2.0f * (s0.w + s1.w);
  *(float4*)&out[i] = o;
}

// ---- launcher --------------------------------------------------------------
extern "C" void kernel_launch(void* const* d_in, const int* in_sizes, int n_in,
                              void* d_out, int out_size, void* d_ws, size_t ws_size,
                              hipStream_t stream) {
  const float* text   = (const float*)d_in[0];
  const float* visual = (const float*)d_in[1];
  const float* W1     = (const float*)d_in[2];
  const float* W2     = (const float*)d_in[3];
  const float* W3     = (const float*)d_in[4];
  float* out = (float*)d_out;

  // Workspace (floats): A,kw2t,kw3v (S each), Q0..Q3, Spart0..1, T
  // Total = 3*393216 + 4*262144 + 2*262144 + 512 = 2,753,024 fl = 11.0 MB
  const size_t S = (size_t)NN * DD, Ssm = (size_t)NN * MM;
  float* ws    = (float*)d_ws;
  float* A     = ws;
  float* kw2t  = ws + S;
  float* kw3v  = ws + 2 * S;
  float* Q     = ws + 3 * S;
  float* Spart = Q + 4 * Ssm;
  float* T     = Spart + 2 * Ssm;

  hipLaunchKernelGGL(tsum_kernel, dim3(NN), dim3(64), 0, stream, text, T);
  hipLaunchKernelGGL(gemm3_kernel, dim3(DD / 64, NN / 32, 3), dim3(256), 0, stream,
                     text, visual, W1, W2, W3, A, kw2t, kw3v);
  hipLaunchKernelGGL(cgemm_kernel, dim3(MM / 64, NN / 32, 4), dim3(256), 0, stream,
                     A, visual, Q);
  hipLaunchKernelGGL(main_kernel, dim3(MM / 32, NN / 16, 2), dim3(256), 0, stream,
                     text, kw2t, kw3v, Q, Spart);
  hipLaunchKernelGGL(combine_kernel, dim3(Ssm / 1024), dim3(256), 0, stream,
                     Spart, T, out);
}